// Round 13
// baseline (33.207 us; speedup 1.0000x reference)
//
#include <hip/hip_runtime.h>

// Delay-logistic DDE, forward Euler, d independent scalar components.
// x_{i+1} = x_i * m_i,  m_i = (1+a) - a*th1*y_i;  y_i = x(i-100) (hist = x_0).
// Output: out[j*(N+1) + t] = x_t  (row-major [d, N+1]).
//
// Round 13 = round 12 (producer/consumer waves, zero recompute, one block owns
// its 64 rows' full 256KB span -> L2-merged full-line HBM writes) MINUS the
// per-tile __syncthreads. The barrier forced s_waitcnt vmcnt(0): every tile,
// every consumer fully retired ~11KB of stores before proceeding (10 bulk-
// synchronous drains/block ~ the 32.5-vs-24us gap). Replaced with LDS flag
// sync + lgkmcnt-ONLY fences:
//   - consumer releases a buffer after its ds_READS complete (flag ds_write
//     is in-order in the per-wave DS queue after the reads); its global
//     stores stay in flight across tiles (vmcnt never drained in-loop).
//   - producer publishes a tile after its ds_writes complete (lgkmcnt(0));
//     DS in-order => consumers seeing the flag see the data.
// Flags are volatile LDS + explicit sched_barrier/lgkmcnt fences (round 6
// lesson: cross-lane LDS needs explicit ordering; atomics with RELEASE would
// re-emit vmcnt(0) drains, defeating the point).
//
// Kept: h[100] in VGPRs via macro-LITERAL indices + (256,1) (rounds 2-5:
// default occupancy target force-spills h -> +67MB HBM spill writes).

constexpr int NT   = 1000;          // N steps (setup_inputs: N=1000)
constexpr int NTAU = 100;           // delay = steps per tile
constexpr int NGRP = NT / NTAU;     // 10 tiles
constexpr int NP1  = NT + 1;        // 1001 columns per row
constexpr int COMP = 64;            // components per block (= producer lanes)
constexpr int LSTR = NTAU + 1;      // 101 dwords: odd stride -> conflict-free
constexpr int NCW  = 3;             // consumer waves

// Literal-index repetition macros (SROA-proof: every h index is a literal).
#define R5(F,B)   F(B) F((B)+1) F((B)+2) F((B)+3) F((B)+4)
#define R25(F,B)  R5(F,B) R5(F,(B)+5) R5(F,(B)+10) R5(F,(B)+15) R5(F,(B)+20)
#define R50(F,B)  R25(F,B) R25(F,(B)+25)
#define R100(F)   R50(F,0) R50(F,50)

// LDS-only ordering point: pins compiler order and drains the DS pipe.
// NEVER waits on vmcnt -> global stores keep streaming.
#define LDS_ORDER() do {                                    \
    __builtin_amdgcn_sched_barrier(0);                      \
    asm volatile("s_waitcnt lgkmcnt(0)" ::: "memory");      \
    __builtin_amdgcn_sched_barrier(0);                      \
} while (0)

__global__ __launch_bounds__(256, 1)   // min 1 wave/EU: full VGPR budget
void ndde_kernel(const float* __restrict__ x0,
                 const float* __restrict__ tau,
                 const float* __restrict__ params,
                 float* __restrict__ out)
{
    __shared__ float buf[2][COMP][LSTR];   // 51,712 B double-buffered tile
    __shared__ int   prodf;                // tiles staged by producer
    __shared__ int   consf[NCW];           // tiles consumed, per consumer wave
    const int tid  = threadIdx.x;
    const int wid  = tid >> 6;             // 0 = producer, 1..3 = consumers
    const int lane = tid & 63;
    const int jbase = (int)blockIdx.x * COMP;

    const float dt = 0.01f * tau[0];
    const float a  = dt * params[0];        // dt * theta0
    const float q  = -(a * params[1]);      // -dt*theta0*theta1
    const float p  = 1.0f + a;

    if (tid == 0) { prodf = 0; consf[0] = 0; consf[1] = 0; consf[2] = 0; }
    __syncthreads();                        // flag init only (once; queues empty)

    volatile int* vprod = &prodf;
    volatile int* vcons = consf;

    if (wid == 0) {
        // ---------------- producer ----------------
        float x = x0[jbase + lane];
        float h[NTAU];                      // history; lives in VGPRs
#define INIT_H(K) h[(K)] = x;
        R100(INIT_H)
#define STEP(K) { const float y_ = h[(K)]; h[(K)] = x; x *= fmaf(q, y_, p); }
#define STG(K)  bp[(K)] = h[(K)];

#pragma clang loop unroll(disable)          // keep ~300-instr body I-cache-resident
        for (int g = 0; g < NGRP; ++g) {
            if (g >= 2) {                   // buf[g&1] holds tile g-2: wait consumed
                while (vcons[0] < g - 1 || vcons[1] < g - 1 || vcons[2] < g - 1)
                    __builtin_amdgcn_s_sleep(1);
                LDS_ORDER();                // poll -> overwrite (cross-wave WAR)
            }
            R100(STEP)                      // h[k] = x_{100g+k}
            float* bp = &buf[g & 1][lane][0];
            R100(STG)                       // stage (stride-101: conflict-free)
            LDS_ORDER();                    // data writes drain before flag (RAW)
            *vprod = g + 1;                 // publish tile g
        }
        // Final column t = N: x = x_1000.
        out[(jbase + lane) * NP1 + NT] = x;
    } else {
        // ---------------- consumers ----------------
        const int cw = wid - 1;
        float* gpb = out + jbase * NP1 + lane;
#pragma clang loop unroll(disable)
        for (int g = 0; g < NGRP; ++g) {
            while (*vprod < g + 1)          // wait for tile g
                __builtin_amdgcn_s_sleep(1);
            LDS_ORDER();                    // poll -> data reads (cross-wave RAW)
            const float* bb = &buf[g & 1][0][0];
            float* gp = gpb + g * NTAU;
            for (int r = cw; r < COMP; r += NCW) {
                const float* lr = bb + r * LSTR;
                float* rp = gp + r * NP1;
                rp[0] = lr[lane];                   // t = 100g + 0..63 (256B)
                if (lane < NTAU - 64)
                    rp[64] = lr[64 + lane];         // t = 100g + 64..99 (144B)
            }
            LDS_ORDER();                    // ds_reads drained (stores NOT waited)
            vcons[cw] = g + 1;              // release buf[g&1]
        }
    }
}

extern "C" void kernel_launch(void* const* d_in, const int* in_sizes, int n_in,
                              void* d_out, int out_size, void* d_ws, size_t ws_size,
                              hipStream_t stream) {
    const float* x0     = (const float*)d_in[0];
    const float* tau    = (const float*)d_in[1];
    const float* params = (const float*)d_in[2];
    float* out = (float*)d_out;
    const int d = in_sizes[0];              // 32768
    const int nblocks = d / COMP;           // 512 blocks x 256 threads
    ndde_kernel<<<nblocks, 256, 0, stream>>>(x0, tau, params, out);
}

// Round 14
// 31.443 us; speedup vs baseline: 1.0561x; 1.0561x over previous
//
#include <hip/hip_runtime.h>

// Delay-logistic DDE, forward Euler, d independent scalar components.
// x_{i+1} = x_i * m_i,  m_i = (1+a) - a*th1*y_i;  y_i = x(i-100) (hist = x_0).
// Output: out[j*(N+1) + t] = x_t  (row-major [d, N+1]).
//
// Round 14 = round 13 (producer/consumer waves, LDS flag sync, zero
// recompute, block owns its 64 rows' 256KB span) with the consumer drain
// rebuilt. r13 post-mortem: store-ISSUE count is trivial and the per-tile
// vmcnt drain was proven a non-factor (r12 approx r13), so the remaining
// suspect is consumer LATENCY serialization: the old loop was
// ds_read -> dependent store per row, striped r+=3 (12KB jumps). Fix:
//  (1) contiguous row range per consumer wave (0-21 / 22-42 / 43-63):
//      each wave sweeps a sequential ~88KB region in address order;
//  (2) batched reads: unrolled 11-row chunks, 22 independent ds_reads into
//      registers THEN 22 stores -> one lgkm wait per chunk, not per row.
//
// Kept verified machinery: h[100] in VGPRs via macro-LITERAL indices +
// (256,1) (rounds 2-5: default occupancy target force-spills h); LDS_ORDER
// (lgkmcnt-only fences; vmcnt never drained in-loop; round 6: cross-lane LDS
// needs explicit ordering); volatile LDS flags, s_sleep poll.

constexpr int NT   = 1000;          // N steps (setup_inputs: N=1000)
constexpr int NTAU = 100;           // delay = steps per tile
constexpr int NGRP = NT / NTAU;     // 10 tiles
constexpr int NP1  = NT + 1;        // 1001 columns per row
constexpr int COMP = 64;            // components per block (= producer lanes)
constexpr int LSTR = NTAU + 1;      // 101 dwords: odd stride -> conflict-free
constexpr int NCW  = 3;             // consumer waves

// Literal-index repetition macros (SROA-proof: every h index is a literal).
#define R5(F,B)   F(B) F((B)+1) F((B)+2) F((B)+3) F((B)+4)
#define R25(F,B)  R5(F,B) R5(F,(B)+5) R5(F,(B)+10) R5(F,(B)+15) R5(F,(B)+20)
#define R50(F,B)  R25(F,B) R25(F,(B)+25)
#define R100(F)   R50(F,0) R50(F,50)

// LDS-only ordering point: pins compiler order and drains the DS pipe.
// NEVER waits on vmcnt -> global stores keep streaming.
#define LDS_ORDER() do {                                    \
    __builtin_amdgcn_sched_barrier(0);                      \
    asm volatile("s_waitcnt lgkmcnt(0)" ::: "memory");      \
    __builtin_amdgcn_sched_barrier(0);                      \
} while (0)

__global__ __launch_bounds__(256, 1)   // min 1 wave/EU: full VGPR budget
void ndde_kernel(const float* __restrict__ x0,
                 const float* __restrict__ tau,
                 const float* __restrict__ params,
                 float* __restrict__ out)
{
    __shared__ float buf[2][COMP][LSTR];   // 51,712 B double-buffered tile
    __shared__ int   prodf;                // tiles staged by producer
    __shared__ int   consf[NCW];           // tiles consumed, per consumer wave
    const int tid  = threadIdx.x;
    const int wid  = tid >> 6;             // 0 = producer, 1..3 = consumers
    const int lane = tid & 63;
    const int jbase = (int)blockIdx.x * COMP;

    const float dt = 0.01f * tau[0];
    const float a  = dt * params[0];        // dt * theta0
    const float q  = -(a * params[1]);      // -dt*theta0*theta1
    const float p  = 1.0f + a;

    if (tid == 0) { prodf = 0; consf[0] = 0; consf[1] = 0; consf[2] = 0; }
    __syncthreads();                        // flag init only (once; queues empty)

    volatile int* vprod = &prodf;
    volatile int* vcons = consf;

    if (wid == 0) {
        // ---------------- producer ----------------
        float x = x0[jbase + lane];
        float h[NTAU];                      // history; lives in VGPRs
#define INIT_H(K) h[(K)] = x;
        R100(INIT_H)
#define STEP(K) { const float y_ = h[(K)]; h[(K)] = x; x *= fmaf(q, y_, p); }
#define STG(K)  bp[(K)] = h[(K)];

#pragma clang loop unroll(disable)          // keep ~300-instr body I-cache-resident
        for (int g = 0; g < NGRP; ++g) {
            if (g >= 2) {                   // buf[g&1] holds tile g-2: wait consumed
                while (vcons[0] < g - 1 || vcons[1] < g - 1 || vcons[2] < g - 1)
                    __builtin_amdgcn_s_sleep(1);
                LDS_ORDER();                // poll -> overwrite (cross-wave WAR)
            }
            R100(STEP)                      // h[k] = x_{100g+k}
            float* bp = &buf[g & 1][lane][0];
            R100(STG)                       // stage (stride-101: conflict-free)
            LDS_ORDER();                    // data writes drain before flag (RAW)
            *vprod = g + 1;                 // publish tile g
        }
        // Final column t = N: x = x_1000.
        out[(jbase + lane) * NP1 + NT] = x;
    } else {
        // ---------------- consumers ----------------
        const int cw    = wid - 1;
        const int start = (cw == 0) ? 0 : (cw == 1) ? 22 : 43;
        const int cnt   = (cw == 0) ? 22 : 21;           // 22+21+21 = 64
        const int lane2 = (lane < 36) ? lane : 35;       // clamp: no LDS OOB
        float* gpb = out + (jbase + start) * NP1 + lane; // row-contiguous range

#pragma clang loop unroll(disable)
        for (int g = 0; g < NGRP; ++g) {
            while (*vprod < g + 1)          // wait for tile g
                __builtin_amdgcn_s_sleep(1);
            LDS_ORDER();                    // poll -> data reads (cross-wave RAW)
            const float* bb = &buf[g & 1][start][0];
            float* gp = gpb + g * NTAU;

            // Two 11-row chunks: batch 22 independent ds_reads, then 22
            // stores (one lgkm wait per chunk; stores sweep address order).
            float va[11], vb[11];
#pragma unroll
            for (int i = 0; i < 11; ++i) {
                va[i] = bb[i * LSTR + lane];
                vb[i] = bb[i * LSTR + 64 + lane2];
            }
#pragma unroll
            for (int i = 0; i < 11; ++i) {
                float* rp = gp + i * NP1;
                rp[0] = va[i];                      // t = 100g + 0..63  (256B)
                if (lane < NTAU - 64) rp[64] = vb[i]; // t = 100g + 64..99 (144B)
            }
#pragma unroll
            for (int i = 0; i < 11; ++i) {
                if (i < cnt - 11) {                 // uniform per wave (10 or 11)
                    va[i] = bb[(11 + i) * LSTR + lane];
                    vb[i] = bb[(11 + i) * LSTR + 64 + lane2];
                }
            }
#pragma unroll
            for (int i = 0; i < 11; ++i) {
                if (i < cnt - 11) {
                    float* rp = gp + (11 + i) * NP1;
                    rp[0] = va[i];
                    if (lane < NTAU - 64) rp[64] = vb[i];
                }
            }
            LDS_ORDER();                    // ds_reads drained (stores NOT waited)
            vcons[cw] = g + 1;              // release buf[g&1]
        }
    }
}

extern "C" void kernel_launch(void* const* d_in, const int* in_sizes, int n_in,
                              void* d_out, int out_size, void* d_ws, size_t ws_size,
                              hipStream_t stream) {
    const float* x0     = (const float*)d_in[0];
    const float* tau    = (const float*)d_in[1];
    const float* params = (const float*)d_in[2];
    float* out = (float*)d_out;
    const int d = in_sizes[0];              // 32768
    const int nblocks = d / COMP;           // 512 blocks x 256 threads
    ndde_kernel<<<nblocks, 256, 0, stream>>>(x0, tau, params, out);
}